// Round 7
// baseline (23.344 us; speedup 1.0000x reference)
//
#include <hip/hip_runtime.h>

// TransMatch scalarized (validated absmax=0 since R2):
//   score = b + Rw[r0] + sum_p( EW[e_p] + i_p*rw0_p + 0.25*i_p*S_p )
//   S_p = sum_{n in p's 32 nodes} m0_{n>>1} * (EW[node_n] + rwsum_n/max(cnt_n,1))
// R7: structural flattening.
//  - precompute kernel: nib-pack (1MB) + Rw[16] + EW for all 2048 pair
//    entities (batch-invariant scalar tables in d_ws)
//  - main kernel: ONE WAVE per (element,pair). No mid barriers (waves
//    independent), one final barrier to combine 2 partials per element.
//    Hop-2 per lane: 2 int4 row loads -> 8 independent nib gathers.

#define DIM 64
#define NS 16
#define NREL 16

__device__ __forceinline__ int rel4(const unsigned int* __restrict__ nib, int e) {
    return (int)((nib[e >> 3] >> ((e & 7) << 2)) & 15u);
}

// ws layout: nib u32[(n_edge+7)/8] @ 0 ; Rw f32[16] @ RW_OFF ; EWp f32[n_pairs] @ RW_OFF+64
__global__ __launch_bounds__(256) void precompute_kernel(
    const int* __restrict__ e2r,          // (N_EDGE,)
    const int* __restrict__ entity_pairs, // (BS,2) flat
    const float* __restrict__ relation_emb,
    const float* __restrict__ entity_emb,
    const float* __restrict__ scorer_w,
    unsigned int* __restrict__ nib,
    float* __restrict__ Rw,
    float* __restrict__ EWp,
    int n_edge, int n_pairs, int nib_blocks, int ew_blocks)
{
    const int blk = blockIdx.x;
    const int t   = threadIdx.x;
    if (blk < nib_blocks) {
        const int tid = blk * 256 + t;
        const int i = tid * 8;
        if (i + 7 < n_edge) {
            const int4 a = *reinterpret_cast<const int4*>(e2r + i);
            const int4 b = *reinterpret_cast<const int4*>(e2r + i + 4);
            nib[tid] =  (unsigned int)(a.x & 15)
                     | ((unsigned int)(a.y & 15) << 4)
                     | ((unsigned int)(a.z & 15) << 8)
                     | ((unsigned int)(a.w & 15) << 12)
                     | ((unsigned int)(b.x & 15) << 16)
                     | ((unsigned int)(b.y & 15) << 20)
                     | ((unsigned int)(b.z & 15) << 24)
                     | ((unsigned int)(b.w & 15) << 28);
        } else if (i < n_edge) {
            unsigned int w = 0;
            for (int k = 0; k < 8 && i + k < n_edge; ++k)
                w |= ((unsigned int)(e2r[i + k] & 15)) << (4 * k);
            nib[tid] = w;
        }
        return;
    }
    const int j = blk - nib_blocks;
    const float4* W4 = reinterpret_cast<const float4*>(scorer_w);
    if (j < ew_blocks) {
        // 256 threads -> 64 pairs/block; 4 lanes per pair (16 dims each)
        const int q   = j * 64 + (t >> 2);
        const int seg = t & 3;
        if (q < n_pairs) {
            const int e = entity_pairs[q];
            const float4* E4 = reinterpret_cast<const float4*>(entity_emb);
            float v = 0.0f;
            #pragma unroll
            for (int k = 0; k < 4; ++k) {
                const float4 a = E4[(size_t)e * 16 + seg * 4 + k];
                const float4 w = W4[seg * 4 + k];
                v = fmaf(a.x, w.x, v); v = fmaf(a.y, w.y, v);
                v = fmaf(a.z, w.z, v); v = fmaf(a.w, w.w, v);
            }
            v += __shfl_xor(v, 1); v += __shfl_xor(v, 2);
            if (seg == 0) EWp[q] = v;
        }
    } else if (j == ew_blocks) {
        // Rw[r] = dot(relation_emb[r], w); 64 lanes: r = t>>2, seg = t&3
        if (t < 64) {
            const int r = t >> 2, seg = t & 3;
            const float4* R4 = reinterpret_cast<const float4*>(relation_emb);
            float v = 0.0f;
            #pragma unroll
            for (int k = 0; k < 4; ++k) {
                const float4 a = R4[r * 16 + seg * 4 + k];
                const float4 w = W4[seg * 4 + k];
                v = fmaf(a.x, w.x, v); v = fmaf(a.y, w.y, v);
                v = fmaf(a.z, w.z, v); v = fmaf(a.w, w.w, v);
            }
            v += __shfl_xor(v, 1); v += __shfl_xor(v, 2);
            if (seg == 0) Rw[r] = v;
        }
    }
}

__global__ __launch_bounds__(256) void transmatch_main(
    const int* __restrict__ relations,       // (BS,)
    const int* __restrict__ entity_pairs,    // (BS,2)
    const int* __restrict__ train_edges,     // (BS,)
    const int* __restrict__ entity2edges,    // (N_ENT,16)
    const int* __restrict__ edge2entities,   // (N_EDGE,2)
    const float* __restrict__ entity_emb,    // (N_ENT,64)
    const float* __restrict__ scorer_w,      // (64,)
    const float* __restrict__ scorer_b,      // (1,)
    const unsigned int* __restrict__ nib,    // nibble-packed rels
    const float* __restrict__ Rwg,           // (16,)
    const float* __restrict__ EWp,           // (BS*2,)
    float* __restrict__ out)                 // (BS,)
{
    __shared__ float wL[DIM];       // written identically by all 4 waves (benign)
    __shared__ float RwLds[NREL];   // idem
    __shared__ float ewn_l[4][32];  // per-wave region
    __shared__ float part[4][4];    // per-wave: {S_p, rw0_p, c0_p, EW_p}

    const int t    = threadIdx.x;
    const int lane = t & 63;
    const int wv   = t >> 6;
    const int b    = blockIdx.x * 2 + (wv >> 1);  // element
    const int p    = wv & 1;                      // pair side

    // prologue: each wave writes the FULL arrays itself, so in-wave
    // write->read ordering (lgkmcnt) guarantees correctness; other waves'
    // identical writes are benign.
    wL[lane] = scorer_w[lane];
    if (lane < NREL) RwLds[lane] = Rwg[lane];

    const int te  = train_edges[b];
    const int e_p = entity_pairs[b * 2 + p];

    // ---- front: lanes 0-15, edge s of pair p ----
    int m0 = 0, nx = 0, ny = 0;
    float rw1 = 0.0f;
    if (lane < NS) {
        const int edge_s = entity2edges[e_p * NS + lane];
        m0 = (edge_s != te) ? 1 : 0;
        const int rel1 = rel4(nib, edge_s);
        rw1 = m0 ? RwLds[rel1] : 0.0f;
        const int2 nn = reinterpret_cast<const int2*>(edge2entities)[edge_s];
        nx = nn.x; ny = nn.y;
    }
    int   c0  = m0;
    float rw0 = rw1;
    c0  += __shfl_xor(c0, 1);  c0  += __shfl_xor(c0, 2);
    c0  += __shfl_xor(c0, 4);  c0  += __shfl_xor(c0, 8);
    rw0 += __shfl_xor(rw0, 1); rw0 += __shfl_xor(rw0, 2);
    rw0 += __shfl_xor(rw0, 4); rw0 += __shfl_xor(rw0, 8);

    // ---- hop-2: lane l -> node n = l>>1 (of this pair's 32), half h = l&1 ----
    const int srcl = lane >> 2;                      // front lane (n>>1)
    const int ndx  = __shfl(nx, srcl);
    const int ndy  = __shfl(ny, srcl);
    const int node = ((lane >> 1) & 1) ? ndy : ndx;
    const int m0n  = __shfl(m0, srcl);

    const int4 ea = *reinterpret_cast<const int4*>(entity2edges + (size_t)node * NS + (lane & 1) * 8);
    const int4 eb = *reinterpret_cast<const int4*>(entity2edges + (size_t)node * NS + (lane & 1) * 8 + 4);

    const int r0_ = rel4(nib, ea.x), r1_ = rel4(nib, ea.y);
    const int r2_ = rel4(nib, ea.z), r3_ = rel4(nib, ea.w);
    const int r4_ = rel4(nib, eb.x), r5_ = rel4(nib, eb.y);
    const int r6_ = rel4(nib, eb.z), r7_ = rel4(nib, eb.w);

    float rws = 0.0f; int cnt = 0;
    if (ea.x != te) { cnt++; rws += RwLds[r0_]; }
    if (ea.y != te) { cnt++; rws += RwLds[r1_]; }
    if (ea.z != te) { cnt++; rws += RwLds[r2_]; }
    if (ea.w != te) { cnt++; rws += RwLds[r3_]; }
    if (eb.x != te) { cnt++; rws += RwLds[r4_]; }
    if (eb.y != te) { cnt++; rws += RwLds[r5_]; }
    if (eb.z != te) { cnt++; rws += RwLds[r6_]; }
    if (eb.w != te) { cnt++; rws += RwLds[r7_]; }
    rws += __shfl_xor(rws, 1);
    cnt += __shfl_xor(cnt, 1);

    // ---- EW[node]: 8 coalesced passes, 4 rows/pass, 16 lanes/row ----
    {
        const float4* E4  = reinterpret_cast<const float4*>(entity_emb);
        const float4* wL4 = reinterpret_cast<const float4*>(wL);
        const int c = lane & 15;
        const float4 wc = wL4[c];
        #pragma unroll
        for (int q = 0; q < 8; ++q) {
            const int row   = q * 4 + (lane >> 4);
            const int nodeq = __shfl(node, row * 2);
            const float4 ev = E4[(size_t)nodeq * 16 + c];
            float v = 0.0f;
            v = fmaf(ev.x, wc.x, v); v = fmaf(ev.y, wc.y, v);
            v = fmaf(ev.z, wc.z, v); v = fmaf(ev.w, wc.w, v);
            v += __shfl_xor(v, 1); v += __shfl_xor(v, 2);
            v += __shfl_xor(v, 4); v += __shfl_xor(v, 8);
            if (c == 0) ewn_l[wv][row] = v;
        }
    }

    const float ewn = ewn_l[wv][lane >> 1];  // same-wave write->read (lgkmcnt)
    float v = 0.0f;
    if ((lane & 1) == 0 && m0n)
        v = ewn + rws / (float)max(cnt, 1);
    v += __shfl_xor(v, 2);  v += __shfl_xor(v, 4);
    v += __shfl_xor(v, 8);  v += __shfl_xor(v, 16); v += __shfl_xor(v, 32);

    if (lane == 0) {
        part[wv][0] = v;
        part[wv][1] = rw0;
        part[wv][2] = (float)c0;
        part[wv][3] = EWp[b * 2 + p];
    }
    __syncthreads();

    if ((wv & 1) == 0 && lane == 0) {
        const int w0 = wv, w1 = wv + 1;
        const float i0 = 1.0f / fmaxf(part[w0][2], 1.0f);
        const float i1 = 1.0f / fmaxf(part[w1][2], 1.0f);
        const int   r0 = relations[b];
        out[b] = scorer_b[0] + RwLds[r0]
               + part[w0][3] + i0 * part[w0][1] + 0.25f * i0 * part[w0][0]
               + part[w1][3] + i1 * part[w1][1] + 0.25f * i1 * part[w1][0];
    }
}

extern "C" void kernel_launch(void* const* d_in, const int* in_sizes, int n_in,
                              void* d_out, int out_size, void* d_ws, size_t ws_size,
                              hipStream_t stream) {
    const int*   relations     = (const int*)d_in[0];
    const int*   entity_pairs  = (const int*)d_in[1];
    const int*   train_edges   = (const int*)d_in[2];
    const int*   entity2edges  = (const int*)d_in[3];
    const int*   edge2entities = (const int*)d_in[4];
    const int*   edge2relation = (const int*)d_in[5];
    const float* relation_emb  = (const float*)d_in[6];
    const float* entity_emb    = (const float*)d_in[7];
    const float* scorer_w      = (const float*)d_in[8];
    const float* scorer_b      = (const float*)d_in[9];
    float* out = (float*)d_out;

    const int bs      = in_sizes[0];
    const int n_pairs = in_sizes[1];          // BS*2
    const int n_edge  = in_sizes[5];
    const int n_words = (n_edge + 7) / 8;

    unsigned int* nib = (unsigned int*)d_ws;
    const size_t RW_OFF = ((size_t)n_words * 4 + 255) & ~(size_t)255;
    float* Rw  = (float*)((char*)d_ws + RW_OFF);
    float* EWp = Rw + 64;  // 256B after Rw

    const int nib_blocks = (n_words + 255) / 256;
    const int ew_blocks  = (n_pairs + 63) / 64;
    precompute_kernel<<<nib_blocks + ew_blocks + 1, 256, 0, stream>>>(
        edge2relation, entity_pairs, relation_emb, entity_emb, scorer_w,
        nib, Rw, EWp, n_edge, n_pairs, nib_blocks, ew_blocks);

    transmatch_main<<<bs / 2, 256, 0, stream>>>(
        relations, entity_pairs, train_edges, entity2edges, edge2entities,
        entity_emb, scorer_w, scorer_b, nib, Rw, EWp, out);
}